// Round 3
// baseline (750.137 us; speedup 1.0000x reference)
//
#include <hip/hip_runtime.h>
#include <math.h>

// Direct conv with the EXACT provided W (numeric-safety: R2's synthesized-basis
// DFT flipped an atan2 branch cut; R1's exact-W conv passed with 8x margin).
// out[b,f,t]: r = sum_k W[f][k] * x[b, t*100+k-300], i = sum_k W[257+f][k] * x[...]
// mags = sqrt(max(r^2+i^2, eps)); phase = atan2(i+eps, r+eps)
//
// Work split: wave = 64 lanes x 4 freqs = freqs 0..255 (f=256 in epilogue);
// frames wave-uniform (8 per wave, 32 per block) -> x reads are broadcasts
// (conflict-free); W read as lane-contiguous ds_read_b128 from k-major tile
// padded to stride 260 (= 4 mod 32 -> <=2-way, free).

#define BATCH 16
#define NSAMP 160000
#define NF 257
#define NT 1603
#define KLEN 400
#define INC 100
#define PADL 300
#define EPSF 1.1920928955078125e-7f

#define FPB 32                        // frames per block
#define FPW 8                         // frames per wave
#define KC 16                         // k-chunk
#define NCH (KLEN / KC)               // 25
#define XSPAN ((FPB - 1) * INC + KLEN)  // 3500 floats
#define WLD 260                       // padded freq-stride of LDS W tile

__global__ __launch_bounds__(256, 3)
void convstft_v3(const float* __restrict__ x, const float* __restrict__ w,
                 float* __restrict__ out) {
  __shared__ float wrt[KC * WLD];     // real rows, k-major: wrt[k*260 + f]
  __shared__ float wit[KC * WLD];     // imag rows
  __shared__ float xs[XSPAN];
  __shared__ float w256r[KLEN];       // exact W row 256 (real f=256)
  __shared__ float w256i[KLEN];       // exact W row 513 (imag f=256)

  const int tid = threadIdx.x;
  const int b = blockIdx.y;
  const int t0 = blockIdx.x * FPB;
  const int wave = tid >> 6;
  const int lane = tid & 63;
  const int frbase = wave * FPW;      // local first frame of this wave

  // ---- stage x window (zero-padded) ----
  const long xb = (long)b * NSAMP;
  const int base = t0 * INC - PADL;
  for (int i = tid; i < XSPAN; i += 256) {
    int g = base + i;
    xs[i] = (g >= 0 && g < NSAMP) ? x[xb + g] : 0.0f;
  }
  // ---- stage exact rows 256 / 513 ----
  if (tid < KLEN / 4) {
    float4 a = *(const float4*)(w + 256 * KLEN + 4 * tid);
    float4 c = *(const float4*)(w + 513 * KLEN + 4 * tid);
    *(float4*)&w256r[4 * tid] = a;
    *(float4*)&w256i[4 * tid] = c;
  }

  float4 ar[FPW], ai[FPW];            // acc: .x..w = freqs 4*lane..4*lane+3
  #pragma unroll
  for (int j = 0; j < FPW; ++j) {
    ar[j] = make_float4(0.f, 0.f, 0.f, 0.f);
    ai[j] = make_float4(0.f, 0.f, 0.f, 0.f);
  }

  const int k4s = tid & 3;            // staging: k-quad
  const int fs = tid >> 2;            // staging: freq low bits (0..63)

  for (int kc = 0; kc < NCH; ++kc) {
    const int kb = kc * KC;
    __syncthreads();                  // prev chunk consumed (and xs/w256 on kc=0)
    // ---- stage W chunk: k-major transpose, 8 float4 per thread ----
    #pragma unroll
    for (int p = 0; p < 2; ++p) {
      float* dst = p ? wit : wrt;
      #pragma unroll
      for (int rep = 0; rep < 4; ++rep) {
        int f = rep * 64 + fs;
        float4 v = *(const float4*)(w + (long)(p * 257 + f) * KLEN + kb + 4 * k4s);
        dst[(4 * k4s + 0) * WLD + f] = v.x;
        dst[(4 * k4s + 1) * WLD + f] = v.y;
        dst[(4 * k4s + 2) * WLD + f] = v.z;
        dst[(4 * k4s + 3) * WLD + f] = v.w;
      }
    }
    __syncthreads();

    #pragma unroll
    for (int k4 = 0; k4 < KC / 4; ++k4) {
      float4 xq[FPW];                 // 4 k-values per frame (broadcast reads)
      #pragma unroll
      for (int j = 0; j < FPW; ++j)
        xq[j] = *(const float4*)&xs[(frbase + j) * INC + kb + 4 * k4];
      #pragma unroll
      for (int kk = 0; kk < 4; ++kk) {
        const int krow = 4 * k4 + kk;
        float4 wr4 = *(const float4*)&wrt[krow * WLD + 4 * lane];
        float4 wi4 = *(const float4*)&wit[krow * WLD + 4 * lane];
        #pragma unroll
        for (int j = 0; j < FPW; ++j) {
          float xv = (&xq[j].x)[kk];
          ar[j].x = fmaf(wr4.x, xv, ar[j].x);
          ar[j].y = fmaf(wr4.y, xv, ar[j].y);
          ar[j].z = fmaf(wr4.z, xv, ar[j].z);
          ar[j].w = fmaf(wr4.w, xv, ar[j].w);
          ai[j].x = fmaf(wi4.x, xv, ai[j].x);
          ai[j].y = fmaf(wi4.y, xv, ai[j].y);
          ai[j].z = fmaf(wi4.z, xv, ai[j].z);
          ai[j].w = fmaf(wi4.w, xv, ai[j].w);
        }
      }
    }
  }

  // ---- epilogue: mags + phase for freqs 0..255 ----
  const long plane = (long)BATCH * NF * NT;
  const long ob = (long)b * ((long)NF * NT);
  #pragma unroll
  for (int j = 0; j < FPW; ++j) {
    int t = t0 + frbase + j;
    if (t < NT) {
      const float* rp = &ar[j].x;
      const float* ip = &ai[j].x;
      #pragma unroll
      for (int q = 0; q < 4; ++q) {
        int f = 4 * lane + q;
        float r = rp[q], im = ip[q];
        long o = ob + (long)f * NT + t;
        out[o] = sqrtf(fmaxf(r * r + im * im, EPSF));
        out[plane + o] = atan2f(im + EPSF, r + EPSF);
      }
    }
  }

  // ---- f = 256: k split across lanes, butterfly reduce ----
  for (int j = 0; j < FPW; ++j) {
    float r = 0.f, im = 0.f;
    for (int k = lane; k < KLEN; k += 64) {
      float xv = xs[(frbase + j) * INC + k];
      r = fmaf(w256r[k], xv, r);
      im = fmaf(w256i[k], xv, im);
    }
    #pragma unroll
    for (int off = 32; off; off >>= 1) {
      r += __shfl_down(r, off);
      im += __shfl_down(im, off);
    }
    if (lane == 0) {
      int t = t0 + frbase + j;
      if (t < NT) {
        long o = ob + (long)256 * NT + t;
        out[o] = sqrtf(fmaxf(r * r + im * im, EPSF));
        out[plane + o] = atan2f(im + EPSF, r + EPSF);
      }
    }
  }
}

extern "C" void kernel_launch(void* const* d_in, const int* in_sizes, int n_in,
                              void* d_out, int out_size, void* d_ws, size_t ws_size,
                              hipStream_t stream) {
  const float* x = (const float*)d_in[0];   // (16, 160000) fp32
  const float* w = (const float*)d_in[1];   // (514, 1, 400) fp32
  float* out = (float*)d_out;

  dim3 grid((NT + FPB - 1) / FPB, BATCH);   // 51 x 16 = 816 blocks
  convstft_v3<<<grid, dim3(256), 0, stream>>>(x, w, out);
}

// Round 4
// 682.519 us; speedup vs baseline: 1.0991x; 1.0991x over previous
//
#include <hip/hip_runtime.h>
#include <math.h>

// Direct conv with the EXACT provided W. R3's compute loop kept verbatim
// (VALU-bound, conflict-free); epilogue rewritten: out-tile staged in LDS
// (f-major, stride 33, aliasing the dead W-tile region), flushed with
// 32-consecutive-lanes = 32-consecutive-t = one full 128B line per f-row.
// R3's direct scatter stores (4*NT stride between lanes) caused 1.65 GB of
// write-allocate RMW traffic -> 750us memory-bound.

#define BATCH 16
#define NSAMP 160000
#define NF 257
#define NT 1603
#define KLEN 400
#define INC 100
#define PADL 300
#define EPSF 1.1920928955078125e-7f

#define FPB 32                          // frames per block
#define FPW 8                           // frames per wave
#define KC 16                           // k-chunk
#define NCH (KLEN / KC)                 // 25
#define XSPAN ((FPB - 1) * INC + KLEN)  // 3500 floats
#define WLD 260                         // W tile freq-stride (<=2-way banks)
#define TLD 33                          // out-tile row stride [257][33]

#define WTILE (KC * WLD)                // 4160 floats per (r|i) tile
#define OBUFN (NF * TLD)                // 8481 floats (> 2*WTILE = 8320)

__global__ __launch_bounds__(256, 3)
void convstft_v4(const float* __restrict__ x, const float* __restrict__ w,
                 float* __restrict__ out) {
  __shared__ float smem[OBUFN + XSPAN + 2 * KLEN];  // 12781 floats = 51.1 KB
  float* wrt = smem;                  // [KC][WLD] real rows, k-major
  float* wit = smem + WTILE;          // [KC][WLD] imag rows
  float* obuf = smem;                 // [257][TLD] out tile (aliases W region)
  float* xs = smem + OBUFN;           // [XSPAN]
  float* w256r = xs + XSPAN;          // exact W row 256
  float* w256i = w256r + KLEN;        // exact W row 513

  const int tid = threadIdx.x;
  const int b = blockIdx.y;
  const int t0 = blockIdx.x * FPB;
  const int wave = tid >> 6;
  const int lane = tid & 63;
  const int frbase = wave * FPW;

  // ---- stage x window (zero-padded) ----
  const long xb = (long)b * NSAMP;
  const int base = t0 * INC - PADL;
  for (int i = tid; i < XSPAN; i += 256) {
    int g = base + i;
    xs[i] = (g >= 0 && g < NSAMP) ? x[xb + g] : 0.0f;
  }
  // ---- stage exact rows 256 / 513 ----
  if (tid < KLEN / 4) {
    float4 a = *(const float4*)(w + 256 * KLEN + 4 * tid);
    float4 c = *(const float4*)(w + 513 * KLEN + 4 * tid);
    *(float4*)&w256r[4 * tid] = a;
    *(float4*)&w256i[4 * tid] = c;
  }

  float4 ar[FPW], ai[FPW];            // acc: .x..w = freqs 4*lane..4*lane+3
  #pragma unroll
  for (int j = 0; j < FPW; ++j) {
    ar[j] = make_float4(0.f, 0.f, 0.f, 0.f);
    ai[j] = make_float4(0.f, 0.f, 0.f, 0.f);
  }

  const int k4s = tid & 3;            // staging: k-quad
  const int fs = tid >> 2;            // staging: freq low bits (0..63)

  for (int kc = 0; kc < NCH; ++kc) {
    const int kb = kc * KC;
    __syncthreads();                  // prev chunk consumed (and xs/w256 on kc=0)
    #pragma unroll
    for (int p = 0; p < 2; ++p) {
      float* dst = p ? wit : wrt;
      #pragma unroll
      for (int rep = 0; rep < 4; ++rep) {
        int f = rep * 64 + fs;        // 0..255
        float4 v = *(const float4*)(w + (long)(p * 257 + f) * KLEN + kb + 4 * k4s);
        dst[(4 * k4s + 0) * WLD + f] = v.x;
        dst[(4 * k4s + 1) * WLD + f] = v.y;
        dst[(4 * k4s + 2) * WLD + f] = v.z;
        dst[(4 * k4s + 3) * WLD + f] = v.w;
      }
    }
    __syncthreads();

    #pragma unroll
    for (int k4 = 0; k4 < KC / 4; ++k4) {
      float4 xq[FPW];                 // broadcast reads (wave-uniform addr)
      #pragma unroll
      for (int j = 0; j < FPW; ++j)
        xq[j] = *(const float4*)&xs[(frbase + j) * INC + kb + 4 * k4];
      #pragma unroll
      for (int kk = 0; kk < 4; ++kk) {
        const int krow = 4 * k4 + kk;
        float4 wr4 = *(const float4*)&wrt[krow * WLD + 4 * lane];
        float4 wi4 = *(const float4*)&wit[krow * WLD + 4 * lane];
        #pragma unroll
        for (int j = 0; j < FPW; ++j) {
          float xv = (&xq[j].x)[kk];
          ar[j].x = fmaf(wr4.x, xv, ar[j].x);
          ar[j].y = fmaf(wr4.y, xv, ar[j].y);
          ar[j].z = fmaf(wr4.z, xv, ar[j].z);
          ar[j].w = fmaf(wr4.w, xv, ar[j].w);
          ai[j].x = fmaf(wi4.x, xv, ai[j].x);
          ai[j].y = fmaf(wi4.y, xv, ai[j].y);
          ai[j].z = fmaf(wi4.z, xv, ai[j].z);
          ai[j].w = fmaf(wi4.w, xv, ai[j].w);
        }
      }
    }
  }

  // ---- f = 256 (needs xs + w256, which are NOT aliased by obuf) ----
  float r256[FPW], i256[FPW];         // lane 0 holds the reduced value
  #pragma unroll
  for (int j = 0; j < FPW; ++j) {
    float r = 0.f, im = 0.f;
    for (int k = lane; k < KLEN; k += 64) {
      float xv = xs[(frbase + j) * INC + k];
      r = fmaf(w256r[k], xv, r);
      im = fmaf(w256i[k], xv, im);
    }
    #pragma unroll
    for (int off = 32; off; off >>= 1) {
      r += __shfl_down(r, off);
      im += __shfl_down(im, off);
    }
    r256[j] = r;
    i256[j] = im;
  }

  __syncthreads();                    // all wrt/wit reads done -> obuf may alias

  const long plane = (long)BATCH * NF * NT;
  const long ob = (long)b * ((long)NF * NT);

  #pragma unroll
  for (int pl = 0; pl < 2; ++pl) {
    // ---- write pass: thread's 4 freqs x 8 frames into obuf[f][jloc] ----
    #pragma unroll
    for (int j = 0; j < FPW; ++j) {
      int jloc = frbase + j;
      const float* rp = &ar[j].x;
      const float* ip = &ai[j].x;
      #pragma unroll
      for (int q = 0; q < 4; ++q) {
        float r = rp[q], im = ip[q];
        float v = pl == 0 ? sqrtf(fmaxf(r * r + im * im, EPSF))
                          : atan2f(im + EPSF, r + EPSF);
        obuf[(4 * lane + q) * TLD + jloc] = v;
      }
      if (lane == 0) {
        float r = r256[j], im = i256[j];
        float v = pl == 0 ? sqrtf(fmaxf(r * r + im * im, EPSF))
                          : atan2f(im + EPSF, r + EPSF);
        obuf[256 * TLD + jloc] = v;
      }
    }
    __syncthreads();
    // ---- flush: 32 consecutive lanes = 32 consecutive t = one 128B line ----
    const long pb = ob + (pl ? plane : 0);
    for (int it = 0; it < (NF * FPB + 255) / 256; ++it) {
      int idx = it * 256 + tid;
      if (idx < NF * FPB) {
        int f = idx >> 5;
        int tl = idx & 31;
        int t = t0 + tl;
        if (t < NT) out[pb + (long)f * NT + t] = obuf[f * TLD + tl];
      }
    }
    __syncthreads();                  // before next plane overwrites obuf
  }
}

extern "C" void kernel_launch(void* const* d_in, const int* in_sizes, int n_in,
                              void* d_out, int out_size, void* d_ws, size_t ws_size,
                              hipStream_t stream) {
  const float* x = (const float*)d_in[0];   // (16, 160000) fp32
  const float* w = (const float*)d_in[1];   // (514, 1, 400) fp32
  float* out = (float*)d_out;

  dim3 grid((NT + FPB - 1) / FPB, BATCH);   // 51 x 16 = 816 blocks
  convstft_v4<<<grid, dim3(256), 0, stream>>>(x, w, out);
}

// Round 5
// 245.348 us; speedup vs baseline: 3.0574x; 2.7818x over previous
//
#include <hip/hip_runtime.h>
#include <math.h>

// Direct conv, exact W. Lessons baked in:
//  R1: f-tiled blocks -> near-ideal HBM traffic (FETCH 30MB / WRITE 63MB).
//  R3/R4: full-f blocks re-fetch all of W per block (589MB) and thrash L2 ->
//         output write-merging dies -> 22x write amplification. Never again.
//  R4: waves-own-frames makes xs reads wave-uniform broadcasts (conflict-free).
// Structure: grid (t=51, f-tile=2, b=16). Block: 4 waves x 64 lanes;
// lane owns freqs {2*lane, 2*lane+1} of the 128-f tile; wave owns 8 frames.
// W staged k-major [16][132] (stride 132 = 4 mod 32 -> <=2-way, free),
// read as contiguous ds_read_b64. Out-tile t-major [32][130] in LDS
// (aliases dead W region), flushed as full 128B lines. f=256 = column 128
// of the fblk==1 tile via butterfly reduce with exact W rows 256/513.

#define BATCH 16
#define NSAMP 160000
#define NF 257
#define NT 1603
#define KLEN 400
#define INC 100
#define PADL 300
#define EPSF 1.1920928955078125e-7f

#define NFT 128                         // freqs per block tile
#define FPB 32                          // frames per block
#define FPW 8                           // frames per wave
#define KC 16                           // k-chunk
#define NCH (KLEN / KC)                 // 25
#define XSPAN ((FPB - 1) * INC + KLEN)  // 3500
#define WLD 132                         // W tile f-stride
#define OLD 130                         // out tile f-stride (t-major [32][130])

__global__ __launch_bounds__(256, 3)
void convstft_v5(const float* __restrict__ x, const float* __restrict__ w,
                 float* __restrict__ out) {
  __shared__ float smem[2 * KC * WLD + XSPAN + 2 * KLEN];  // 8524 fl = 34.1 KB
  float* wrt = smem;                    // [KC][WLD] real, k-major
  float* wit = smem + KC * WLD;         // [KC][WLD] imag
  float* obuf = smem;                   // [FPB][OLD] aliases W tiles (4160<=4224)
  float* xs = smem + 2 * KC * WLD;      // [XSPAN]
  float* w256r = xs + XSPAN;            // exact W row 256
  float* w256i = w256r + KLEN;          // exact W row 513

  const int tid = threadIdx.x;
  const int t0 = blockIdx.x * FPB;
  const int fblk = blockIdx.y;          // 0: f 0..127; 1: f 128..255 (+256)
  const int b = blockIdx.z;
  const int fBase = fblk * NFT;
  const int wave = tid >> 6;
  const int lane = tid & 63;
  const int frbase = wave * FPW;

  // ---- stage x window (vectorized, zero-padded) ----
  const long xb = (long)b * NSAMP;
  const int base = t0 * INC - PADL;
  for (int i4 = tid; i4 < XSPAN / 4; i4 += 256) {
    int g = base + 4 * i4;
    float4 v;
    if (g >= 0 && g + 3 < NSAMP) {
      v = *(const float4*)(x + xb + g);
    } else {
      v.x = (g + 0 >= 0 && g + 0 < NSAMP) ? x[xb + g + 0] : 0.f;
      v.y = (g + 1 >= 0 && g + 1 < NSAMP) ? x[xb + g + 1] : 0.f;
      v.z = (g + 2 >= 0 && g + 2 < NSAMP) ? x[xb + g + 2] : 0.f;
      v.w = (g + 3 >= 0 && g + 3 < NSAMP) ? x[xb + g + 3] : 0.f;
    }
    *(float4*)&xs[4 * i4] = v;
  }
  if (fblk == 1 && tid < KLEN / 4) {    // exact rows 256 / 513
    float4 a = *(const float4*)(w + 256 * KLEN + 4 * tid);
    float4 c = *(const float4*)(w + 513 * KLEN + 4 * tid);
    *(float4*)&w256r[4 * tid] = a;
    *(float4*)&w256i[4 * tid] = c;
  }

  float2 ar[FPW], ai[FPW];              // .x/.y = freqs 2*lane / 2*lane+1
  #pragma unroll
  for (int j = 0; j < FPW; ++j) {
    ar[j] = make_float2(0.f, 0.f);
    ai[j] = make_float2(0.f, 0.f);
  }

  const int kq = tid & 3;               // staging k-quad
  const int fs = tid >> 2;              // staging f low bits 0..63

  for (int kc = 0; kc < NCH; ++kc) {
    const int kb = kc * KC;
    __syncthreads();                    // prev chunk consumed (xs/w256 on kc=0)
    #pragma unroll
    for (int p = 0; p < 2; ++p) {
      float* dst = p ? wit : wrt;
      #pragma unroll
      for (int rep = 0; rep < 2; ++rep) {
        int lf = rep * 64 + fs;         // 0..127
        float4 v = *(const float4*)(w + (long)(p * 257 + fBase + lf) * KLEN + kb + 4 * kq);
        dst[(4 * kq + 0) * WLD + lf] = v.x;
        dst[(4 * kq + 1) * WLD + lf] = v.y;
        dst[(4 * kq + 2) * WLD + lf] = v.z;
        dst[(4 * kq + 3) * WLD + lf] = v.w;
      }
    }
    __syncthreads();

    #pragma unroll
    for (int k4 = 0; k4 < KC / 4; ++k4) {
      float4 xq[FPW];                   // wave-uniform -> broadcast reads
      #pragma unroll
      for (int j = 0; j < FPW; ++j)
        xq[j] = *(const float4*)&xs[(frbase + j) * INC + kb + 4 * k4];
      #pragma unroll
      for (int kk = 0; kk < 4; ++kk) {
        const int krow = 4 * k4 + kk;
        float2 wr2 = *(const float2*)&wrt[krow * WLD + 2 * lane];
        float2 wi2 = *(const float2*)&wit[krow * WLD + 2 * lane];
        #pragma unroll
        for (int j = 0; j < FPW; ++j) {
          float xv = (&xq[j].x)[kk];
          ar[j].x = fmaf(wr2.x, xv, ar[j].x);
          ar[j].y = fmaf(wr2.y, xv, ar[j].y);
          ai[j].x = fmaf(wi2.x, xv, ai[j].x);
          ai[j].y = fmaf(wi2.y, xv, ai[j].y);
        }
      }
    }
  }

  // ---- f = 256 (fblk==1): k split across lanes, butterfly reduce ----
  float r256[FPW], i256[FPW];
  if (fblk == 1) {
    #pragma unroll
    for (int j = 0; j < FPW; ++j) {
      float r = 0.f, im = 0.f;
      for (int k = lane; k < KLEN; k += 64) {
        float xv = xs[(frbase + j) * INC + k];
        r = fmaf(w256r[k], xv, r);
        im = fmaf(w256i[k], xv, im);
      }
      #pragma unroll
      for (int off = 32; off; off >>= 1) {
        r += __shfl_down(r, off);
        im += __shfl_down(im, off);
      }
      r256[j] = r;
      i256[j] = im;
    }
  }

  __syncthreads();                      // all W-tile reads done -> obuf may alias

  const long plane = (long)BATCH * NF * NT;
  const long ob = (long)b * ((long)NF * NT) + (long)fBase * NT;
  const int ncols = fblk ? NFT + 1 : NFT;

  #pragma unroll
  for (int pl = 0; pl < 2; ++pl) {
    #pragma unroll
    for (int j = 0; j < FPW; ++j) {
      int jl = frbase + j;
      float2 v;
      if (pl == 0) {
        v.x = sqrtf(fmaxf(ar[j].x * ar[j].x + ai[j].x * ai[j].x, EPSF));
        v.y = sqrtf(fmaxf(ar[j].y * ar[j].y + ai[j].y * ai[j].y, EPSF));
      } else {
        v.x = atan2f(ai[j].x + EPSF, ar[j].x + EPSF);
        v.y = atan2f(ai[j].y + EPSF, ar[j].y + EPSF);
      }
      *(float2*)&obuf[jl * OLD + 2 * lane] = v;   // contiguous b64, conflict-free
      if (fblk == 1 && lane == 0) {
        float rr = r256[j], ii = i256[j];
        obuf[jl * OLD + 128] = (pl == 0)
            ? sqrtf(fmaxf(rr * rr + ii * ii, EPSF))
            : atan2f(ii + EPSF, rr + EPSF);
      }
    }
    __syncthreads();
    // flush: 32 consecutive lanes = 32 consecutive t = one 128B line per f-row
    const long pb = ob + (pl ? plane : 0);
    for (int it = 0; it < 17; ++it) {
      int idx = it * 256 + tid;
      if (idx < ncols * FPB) {
        int lf = idx >> 5;
        int tl = idx & 31;
        int t = t0 + tl;
        if (t < NT) out[pb + (long)lf * NT + t] = obuf[tl * OLD + lf];
      }
    }
    __syncthreads();                    // before next plane reuses obuf
  }
}

extern "C" void kernel_launch(void* const* d_in, const int* in_sizes, int n_in,
                              void* d_out, int out_size, void* d_ws, size_t ws_size,
                              hipStream_t stream) {
  const float* x = (const float*)d_in[0];   // (16, 160000) fp32
  const float* w = (const float*)d_in[1];   // (514, 1, 400) fp32
  float* out = (float*)d_out;

  dim3 grid((NT + FPB - 1) / FPB, 2, BATCH);  // 51 x 2 x 16 = 1632 blocks
  convstft_v5<<<grid, dim3(256), 0, stream>>>(x, w, out);
}